// Round 14
// baseline (408.451 us; speedup 1.0000x reference)
//
#include <hip/hip_runtime.h>
#include <hip/hip_bf16.h>
#include <hip/hip_fp16.h>

static constexpr int N_NODES  = 100000;
static constexpr int N_EDGES  = 1600000;
static constexpr int DIM_IN   = 768;
static constexpr int DIM_H    = 128;
static constexpr int N_GRAPHS = 64;
static constexpr int NB_SCAN  = (N_NODES + 255) / 256;   // 391

typedef __attribute__((ext_vector_type(8))) _Float16 half8;
typedef __attribute__((ext_vector_type(4))) float f32x4;

__device__ __forceinline__ void gld16(const void* g, void* l) {
    __builtin_amdgcn_global_load_lds(
        (const __attribute__((address_space(1))) void*)g,
        (__attribute__((address_space(3))) void*)l, 16, 0, 0);
}

// ---------------------------------------------------------------- degree
__global__ void k_indeg(const int* __restrict__ edst, int* __restrict__ indeg) {
    int e = blockIdx.x * 256 + threadIdx.x;
    if (e < N_EDGES) atomicAdd(&indeg[edst[e]], 1);
}

// ---------------------------------------------------------------- W convert (both layers, fp16 transposed)
__global__ void k_convW(const float* __restrict__ W1, const float* __restrict__ W2,
                        _Float16* __restrict__ W1t, _Float16* __restrict__ W2t) {
    int i = blockIdx.x * 256 + threadIdx.x;
    const int total1 = DIM_IN * DIM_H;
    if (i < total1) {
        int k = i >> 7, n = i & 127;
        W1t[(size_t)n * DIM_IN + k] = (_Float16)W1[i];
    } else if (i < total1 + DIM_H * DIM_H) {
        int j = i - total1;
        int k = j >> 7, n = j & 127;
        W2t[(size_t)n * DIM_H + k] = (_Float16)W2[j];
    }
}

// ---------------------------------------------------------------- scan (+dis fold)
__global__ void k_scan1(const int* __restrict__ indeg, int* __restrict__ rp,
                        int* __restrict__ bsum, float* __restrict__ dis) {
    __shared__ int s[256];
    int t = threadIdx.x;
    int i = blockIdx.x * 256 + t;
    int v = (i < N_NODES) ? indeg[i] : 0;
    s[t] = v;
    __syncthreads();
    for (int off = 1; off < 256; off <<= 1) {
        int x = (t >= off) ? s[t - off] : 0;
        __syncthreads();
        s[t] += x;
        __syncthreads();
    }
    if (i < N_NODES) {
        rp[i] = s[t] - v;                       // exclusive (block-local)
        dis[i] = rsqrtf((float)v + 1.0f);       // +1 = self loop
    }
    if (t == 255) bsum[blockIdx.x] = s[255];
}

// scan of block sums + gstart binary searches on idle threads
__global__ void k_scan2(int* __restrict__ bsum, const int* __restrict__ batch,
                        int* __restrict__ gstart) {
    __shared__ int s[512];
    int t = threadIdx.x;
    int v = (t < NB_SCAN) ? bsum[t] : 0;
    s[t] = v;
    __syncthreads();
    for (int off = 1; off < 512; off <<= 1) {
        int x = (t >= off) ? s[t - off] : 0;
        __syncthreads();
        s[t] += x;
        __syncthreads();
    }
    if (t < NB_SCAN) bsum[t] = s[t] - v;        // exclusive block offsets
    if (t <= N_GRAPHS) {                        // lower_bound(batch, t)
        int lo = 0, hi = N_NODES;
        while (lo < hi) {
            int mid = (lo + hi) >> 1;
            if (batch[mid] < t) lo = mid + 1; else hi = mid;
        }
        gstart[t] = lo;
    }
}

// ---------------------------------------------------------------- MFMA GEMM
// 64x128 tile, BK=32, async global_load_lds double-buffer, counted vmcnt
// (never 0 in main loop), raw s_barrier. A fp32 in LDS with XOR-swizzled
// SOURCE address (linear LDS dest, swizzled read — guide rule #21);
// fp32->fp16 at fragment read. W fp16 linear ([128][32]: row stride 16
// dwords is conflict-minimal). LDS 32 KB -> 4 blocks/CU.
#define BKQ 32

template<int K, bool AFP32, bool FUSE_SCATTER>
__global__ __launch_bounds__(256) void k_gemm_mfma(const void* __restrict__ Av,
                                                   const _Float16* __restrict__ Wt,
                                                   _Float16* __restrict__ C,
                                                   int nrows,
                                                   const int* __restrict__ esrc,
                                                   const int* __restrict__ edst,
                                                   const int* __restrict__ rp,
                                                   const int* __restrict__ bsum,
                                                   const float* __restrict__ dis,
                                                   int* __restrict__ cursor,
                                                   uint2* __restrict__ csrw,
                                                   int gemm_blocks) {
    __shared__ uint Asb[2][2048];   // A tile: fp32 [64][32] (8KB) / fp16 [64][32] (4KB)
    __shared__ uint Wsb[2][2048];   // W tile: fp16 [128][32] (8KB)

    if (FUSE_SCATTER && (int)blockIdx.x >= gemm_blocks) {
        int e = (blockIdx.x - gemm_blocks) * 256 + threadIdx.x;
        if (e < N_EDGES) {
            int d = edst[e];
            int sv = esrc[e];
            int pos = atomicAdd(&cursor[d], 1);
            uint2 val;
            val.x = (uint)sv;
            val.y = __float_as_uint(dis[sv]);
            csrw[rp[d] + bsum[d >> 8] + pos] = val;
        }
        return;
    }

    const int t = threadIdx.x;
    const int row0 = blockIdx.x * 64;
    const int l = t & 63;
    const int wv = t >> 6;
    const int wm = wv >> 1, wn = wv & 1;  // wave 2x2: 32 rows x 64 cols each
    const int lr = l & 15;
    const int lk8 = (l >> 4) * 8;         // k-offset of fragment: 0/8/16/24
    constexpr int NT = K / BKQ;

    // ---- staging lambda: issue async loads for K-window k0 into buffer b ----
    auto stage = [&](int b, int k0) {
        if (AFP32) {
            // A fp32 [64][32] = 8 chunks of 1KB; wave wv owns chunks 2wv,2wv+1.
            #pragma unroll
            for (int j = 0; j < 2; ++j) {
                int c = 2 * wv + j;
                int row = c * 8 + (l >> 3);
                int grow = min(row0 + row, nrows - 1);
                int dkb = (l & 7) * 4;
                int sdk = dkb ^ ((row & 7) << 2);   // source swizzle (read undoes it)
                const float* gp = (const float*)Av + (size_t)grow * K + k0 + sdk;
                gld16(gp, &Asb[b][c * 256]);
            }
        } else {
            // A fp16 [64][32] = 4 chunks; wave wv owns chunk wv.
            int c = wv;
            int row = c * 16 + (l >> 2);
            int grow = min(row0 + row, nrows - 1);
            int dwb = (l & 3) * 4;                  // dword within 16-dword row
            const _Float16* gp = (const _Float16*)Av + (size_t)grow * K + k0 + dwb * 2;
            gld16(gp, &Asb[b][c * 256]);
        }
        // W fp16 [128][32] = 8 chunks; wave wv owns chunks 2wv,2wv+1.
        #pragma unroll
        for (int j = 0; j < 2; ++j) {
            int c = 2 * wv + j;
            int n = c * 16 + (l >> 2);
            int dwb = (l & 3) * 4;
            const _Float16* gp = Wt + (size_t)n * K + k0 + dwb * 2;
            gld16(gp, &Wsb[b][c * 256]);
        }
    };

    f32x4 acc[2][4];
    const f32x4 zero = {0.f, 0.f, 0.f, 0.f};
    #pragma unroll
    for (int m = 0; m < 2; ++m)
        #pragma unroll
        for (int n = 0; n < 4; ++n) acc[m][n] = zero;

    stage(0, 0);
    for (int tt = 0; tt < NT; ++tt) {
        const int bb = tt & 1;
        if (tt + 1 < NT) {
            stage(bb ^ 1, (tt + 1) * BKQ);
            // wait only for THIS step's loads; next step's stay in flight
            if constexpr (AFP32) asm volatile("s_waitcnt vmcnt(4)" ::: "memory");
            else                 asm volatile("s_waitcnt vmcnt(3)" ::: "memory");
        } else {
            asm volatile("s_waitcnt vmcnt(0)" ::: "memory");
        }
        __builtin_amdgcn_s_barrier();
        asm volatile("" ::: "memory");

        // ---- fragments ----
        half8 af[2];
        #pragma unroll
        for (int m = 0; m < 2; ++m) {
            int row_l = wm * 32 + m * 16 + lr;
            if (AFP32) {
                int x = (row_l & 7) << 2;
                const uint* base = &Asb[bb][row_l * 32];
                float4 f0 = *(const float4*)&base[lk8 ^ x];
                float4 f1 = *(const float4*)&base[(lk8 + 4) ^ x];
                half8 r;
                r[0] = (_Float16)f0.x; r[1] = (_Float16)f0.y;
                r[2] = (_Float16)f0.z; r[3] = (_Float16)f0.w;
                r[4] = (_Float16)f1.x; r[5] = (_Float16)f1.y;
                r[6] = (_Float16)f1.z; r[7] = (_Float16)f1.w;
                af[m] = r;
            } else {
                const ushort* base = (const ushort*)&Asb[bb][0];
                af[m] = *(const half8*)&base[row_l * 32 + lk8];
            }
        }
        half8 wf[4];
        #pragma unroll
        for (int n = 0; n < 4; ++n) {
            int nn = wn * 64 + n * 16 + lr;
            const ushort* base = (const ushort*)&Wsb[bb][0];
            wf[n] = *(const half8*)&base[nn * 32 + lk8];
        }
        #pragma unroll
        for (int m = 0; m < 2; ++m)
            #pragma unroll
            for (int n = 0; n < 4; ++n)
                acc[m][n] = __builtin_amdgcn_mfma_f32_16x16x32_f16(af[m], wf[n], acc[m][n], 0, 0, 0);

        asm volatile("" ::: "memory");
        __builtin_amdgcn_s_barrier();   // all waves done reading buf before overwrite
    }

    // ---- epilogue: C/D layout col=lane&15, row=(lane>>4)*4+j ----
    #pragma unroll
    for (int m = 0; m < 2; ++m) {
        #pragma unroll
        for (int n = 0; n < 4; ++n) {
            int col = wn * 64 + n * 16 + lr;
            #pragma unroll
            for (int j = 0; j < 4; ++j) {
                int row = row0 + wm * 32 + m * 16 + (l >> 4) * 4 + j;
                if (row < nrows)
                    C[(size_t)row * DIM_H + col] = (_Float16)acc[m][n][j];
            }
        }
    }
}

// ---------------------------------------------------------------- aggregation (R7 structure, fp16 features)
__device__ __forceinline__ void acc8(uint4 u, float w, float* a) {
    __half2 h0 = *(__half2*)&u.x;
    __half2 h1 = *(__half2*)&u.y;
    __half2 h2 = *(__half2*)&u.z;
    __half2 h3 = *(__half2*)&u.w;
    a[0] += __low2float(h0) * w; a[1] += __high2float(h0) * w;
    a[2] += __low2float(h1) * w; a[3] += __high2float(h1) * w;
    a[4] += __low2float(h2) * w; a[5] += __high2float(h2) * w;
    a[6] += __low2float(h3) * w; a[7] += __high2float(h3) * w;
}

__global__ __launch_bounds__(256) void k_agg(const _Float16* __restrict__ hin,
                                             const uint2* __restrict__ csrw,
                                             const int* __restrict__ rp,
                                             const int* __restrict__ bsum,
                                             const int* __restrict__ indeg,
                                             const float* __restrict__ dis,
                                             const float* __restrict__ bias,
                                             _Float16* __restrict__ hout) {
    int node = (blockIdx.x * 256 + threadIdx.x) >> 6;
    int lane = threadIdx.x & 63;
    if (node >= N_NODES) return;
    int q  = lane >> 4;          // quarter 0..3
    int cl = lane & 15;          // 8-channel group within row
    float di = dis[node];
    int beg = rp[node] + bsum[node >> 8];
    int cnt = indeg[node];

    float a[8] = {0.f, 0.f, 0.f, 0.f, 0.f, 0.f, 0.f, 0.f};

    // prologue group: {self, e0, e1, e2}
    {
        uint s; float w;
        if (q == 0)             { s = (uint)node; w = di * di; }
        else if (q - 1 < cnt)   { uint2 p = csrw[beg + q - 1]; s = p.x; w = __uint_as_float(p.y) * di; }
        else                    { s = (uint)node; w = 0.f; }
        uint4 u = ((const uint4*)(hin + (size_t)s * DIM_H))[cl];
        acc8(u, w, a);
    }
    const uint2* cp = csrw + beg + 3;
    int m = cnt - 3;
    int i = 0;
    for (; i + 8 <= m; i += 8) {
        uint2 p0 = cp[i + q];
        uint2 p1 = cp[i + 4 + q];
        float w0 = __uint_as_float(p0.y) * di;
        float w1 = __uint_as_float(p1.y) * di;
        uint4 u0 = ((const uint4*)(hin + (size_t)p0.x * DIM_H))[cl];
        uint4 u1 = ((const uint4*)(hin + (size_t)p1.x * DIM_H))[cl];
        acc8(u0, w0, a);
        acc8(u1, w1, a);
    }
    for (; i < m; i += 4) {
        int idx = i + q;
        uint s; float w;
        if (idx < m) { uint2 p = cp[idx]; s = p.x; w = __uint_as_float(p.y) * di; }
        else         { s = (uint)node;    w = 0.f; }
        uint4 u = ((const uint4*)(hin + (size_t)s * DIM_H))[cl];
        acc8(u, w, a);
    }

    #pragma unroll
    for (int j = 0; j < 8; ++j) {
        a[j] += __shfl_xor(a[j], 16);
        a[j] += __shfl_xor(a[j], 32);
    }

    if (q == 0) {
        float4 b0 = ((const float4*)bias)[cl * 2];
        float4 b1 = ((const float4*)bias)[cl * 2 + 1];
        __half2 h0 = __floats2half2_rn(fmaxf(a[0] + b0.x, 0.f), fmaxf(a[1] + b0.y, 0.f));
        __half2 h1 = __floats2half2_rn(fmaxf(a[2] + b0.z, 0.f), fmaxf(a[3] + b0.w, 0.f));
        __half2 h2 = __floats2half2_rn(fmaxf(a[4] + b1.x, 0.f), fmaxf(a[5] + b1.y, 0.f));
        __half2 h3 = __floats2half2_rn(fmaxf(a[6] + b1.z, 0.f), fmaxf(a[7] + b1.w, 0.f));
        uint4 o;
        o.x = *(uint*)&h0; o.y = *(uint*)&h1; o.z = *(uint*)&h2; o.w = *(uint*)&h3;
        ((uint4*)(hout + (size_t)node * DIM_H))[cl] = o;
    }
}

// ---------------------------------------------------------------- mean pool: per-split partials
#define PSPLIT 8
__global__ __launch_bounds__(256) void k_pool(const _Float16* __restrict__ h,
                                              const int* __restrict__ gstart,
                                              float* __restrict__ pooled2) {
    int g  = blockIdx.x >> 3;
    int sp = blockIdx.x & 7;
    int r0 = gstart[g], r1 = gstart[g + 1];
    int count = r1 - r0;
    int chunk = (count + PSPLIT - 1) / PSPLIT;
    int aS = r0 + sp * chunk;
    int bE = min(aS + chunk, r1);
    int c  = threadIdx.x & 63;       // uint channel pair
    int rr = threadIdx.x >> 6;       // row offset 0..3
    float s0a = 0.f, s1a = 0.f, s0b = 0.f, s1b = 0.f;
    int r = aS + rr;
    for (; r + 4 < bE; r += 8) {     // 2-way unroll, independent accumulators
        uint ua = ((const uint*)(h + (size_t)r * DIM_H))[c];
        uint ub = ((const uint*)(h + (size_t)(r + 4) * DIM_H))[c];
        __half2 ha = *(__half2*)&ua;
        __half2 hb = *(__half2*)&ub;
        s0a += __low2float(ha); s1a += __high2float(ha);
        s0b += __low2float(hb); s1b += __high2float(hb);
    }
    if (r < bE) {
        uint ua = ((const uint*)(h + (size_t)r * DIM_H))[c];
        __half2 ha = *(__half2*)&ua;
        s0a += __low2float(ha); s1a += __high2float(ha);
    }
    float s0 = s0a + s0b, s1 = s1a + s1b;
    __shared__ float sm0[4][64], sm1[4][64];
    sm0[rr][c] = s0; sm1[rr][c] = s1;
    __syncthreads();
    if (rr == 0) {
        float v0 = sm0[0][c] + sm0[1][c] + sm0[2][c] + sm0[3][c];
        float v1 = sm1[0][c] + sm1[1][c] + sm1[2][c] + sm1[3][c];
        float* dst = pooled2 + (size_t)(g * PSPLIT + sp) * DIM_H;
        dst[2 * c]     = v0;
        dst[2 * c + 1] = v1;
    }
}

// ---------------------------------------------------------------- head (sums 8 partials)
__global__ __launch_bounds__(128) void k_head(const float* __restrict__ pooled2,
                                              const int* __restrict__ gstart,
                                              const float* __restrict__ Wh,
                                              const float* __restrict__ bh,
                                              float* __restrict__ out) {
    int g = blockIdx.x;
    int c = threadIdx.x;
    float s = 0.f;
    #pragma unroll
    for (int sp = 0; sp < PSPLIT; ++sp)
        s += pooled2[(size_t)(g * PSPLIT + sp) * DIM_H + c];
    float cntg = (float)(gstart[g + 1] - gstart[g]);
    float e = s / fmaxf(cntg, 1.0f);
    __shared__ float s0[128], s1[128];
    s0[c] = e * Wh[c * 2 + 0];
    s1[c] = e * Wh[c * 2 + 1];
    __syncthreads();
    for (int off = 64; off > 0; off >>= 1) {
        if (c < off) { s0[c] += s0[c + off]; s1[c] += s1[c + off]; }
        __syncthreads();
    }
    if (c == 0) {
        out[g * 2 + 0] = s0[0] + bh[0];
        out[g * 2 + 1] = s1[0] + bh[1];
    }
}

// ---------------------------------------------------------------- launch
extern "C" void kernel_launch(void* const* d_in, const int* in_sizes, int n_in,
                              void* d_out, int out_size, void* d_ws, size_t ws_size,
                              hipStream_t stream) {
    const float* x    = (const float*)d_in[0];
    const int*   esrc = (const int*)d_in[1];
    const int*   edst = esrc + N_EDGES;
    const int*   batch= (const int*)d_in[2];
    const float* W1   = (const float*)d_in[3];
    const float* b1   = (const float*)d_in[4];
    const float* W2   = (const float*)d_in[5];
    const float* b2   = (const float*)d_in[6];
    const float* Wh   = (const float*)d_in[7];
    const float* bh   = (const float*)d_in[8];
    float* out = (float*)d_out;

    char* ws = (char*)d_ws;
    size_t off = 0;
    auto alloc = [&](size_t bytes) {
        void* p = ws + off;
        off += (bytes + 255) & ~(size_t)255;
        return p;
    };
    _Float16* bufZ   = (_Float16*)alloc((size_t)N_NODES * DIM_H * 2);
    _Float16* bufH   = (_Float16*)alloc((size_t)N_NODES * DIM_H * 2);
    float*    dis    = (float*)alloc((size_t)N_NODES * 4);
    int*      deg2   = (int*)  alloc((size_t)2 * N_NODES * 4);   // indeg | cursor
    int*      indeg  = deg2;
    int*      cursor = deg2 + N_NODES;
    int*      rp     = (int*)  alloc((size_t)N_NODES * 4);
    uint2*    csrw   = (uint2*)alloc((size_t)N_EDGES * 8);
    int*      bsum   = (int*)  alloc(512 * 4);
    float*    pooled2= (float*)alloc((size_t)N_GRAPHS * PSPLIT * DIM_H * 4);
    int*      gstart = (int*)  alloc((N_GRAPHS + 1) * 4);
    _Float16* W1t    = (_Float16*)alloc((size_t)DIM_IN * DIM_H * 2);
    _Float16* W2t    = (_Float16*)alloc((size_t)DIM_H * DIM_H * 2);

    hipMemsetAsync(deg2, 0, (size_t)2 * N_NODES * 4, stream);

    int convblocks = (DIM_IN * DIM_H + DIM_H * DIM_H + 255) / 256;
    k_convW  <<<convblocks, 256, 0, stream>>>(W1, W2, W1t, W2t);

    k_indeg  <<<(N_EDGES + 255) / 256, 256, 0, stream>>>(edst, indeg);
    k_scan1  <<<NB_SCAN, 256, 0, stream>>>(indeg, rp, bsum, dis);
    k_scan2  <<<1, 512, 0, stream>>>(bsum, batch, gstart);

    int gblocks = (N_NODES + 63) / 64;                   // 1563
    int scblocks = (N_EDGES + 255) / 256;                // 6250
    // GEMM1 with CSR scatter streamed behind it
    k_gemm_mfma<DIM_IN, true, true><<<gblocks + scblocks, 256, 0, stream>>>(
        x, W1t, bufZ, N_NODES, esrc, edst, rp, bsum, dis, cursor, csrw, gblocks);
    k_agg<<<(N_NODES + 3) / 4, 256, 0, stream>>>(bufZ, csrw, rp, bsum, indeg, dis, b1, bufH);
    k_gemm_mfma<DIM_H, false, false><<<gblocks, 256, 0, stream>>>(
        bufH, W2t, bufZ, N_NODES, nullptr, nullptr, nullptr, nullptr, nullptr, nullptr, nullptr, gblocks);
    k_agg<<<(N_NODES + 3) / 4, 256, 0, stream>>>(bufZ, csrw, rp, bsum, indeg, dis, b2, bufH);

    k_pool<<<N_GRAPHS * PSPLIT, 256, 0, stream>>>(bufH, gstart, pooled2);
    k_head<<<N_GRAPHS, 128, 0, stream>>>(pooled2, gstart, Wh, bh, out);
}

// Round 15
// 396.814 us; speedup vs baseline: 1.0293x; 1.0293x over previous
//
#include <hip/hip_runtime.h>
#include <hip/hip_bf16.h>
#include <hip/hip_fp16.h>

static constexpr int N_NODES  = 100000;
static constexpr int N_EDGES  = 1600000;
static constexpr int DIM_IN   = 768;
static constexpr int DIM_H    = 128;
static constexpr int N_GRAPHS = 64;
static constexpr int NB_SCAN  = (N_NODES + 255) / 256;   // 391

typedef __attribute__((ext_vector_type(8))) _Float16 half8;
typedef __attribute__((ext_vector_type(4))) float f32x4;

// ---------------------------------------------------------------- degree
__global__ void k_indeg(const int* __restrict__ edst, int* __restrict__ indeg) {
    int e = blockIdx.x * 256 + threadIdx.x;
    if (e < N_EDGES) atomicAdd(&indeg[edst[e]], 1);
}

// ---------------------------------------------------------------- W convert (both layers, fp16 transposed)
__global__ void k_convW(const float* __restrict__ W1, const float* __restrict__ W2,
                        _Float16* __restrict__ W1t, _Float16* __restrict__ W2t) {
    int i = blockIdx.x * 256 + threadIdx.x;
    const int total1 = DIM_IN * DIM_H;
    if (i < total1) {
        int k = i >> 7, n = i & 127;
        W1t[(size_t)n * DIM_IN + k] = (_Float16)W1[i];
    } else if (i < total1 + DIM_H * DIM_H) {
        int j = i - total1;
        int k = j >> 7, n = j & 127;
        W2t[(size_t)n * DIM_H + k] = (_Float16)W2[j];
    }
}

// ---------------------------------------------------------------- scan (+dis fold)
__global__ void k_scan1(const int* __restrict__ indeg, int* __restrict__ rp,
                        int* __restrict__ bsum, float* __restrict__ dis) {
    __shared__ int s[256];
    int t = threadIdx.x;
    int i = blockIdx.x * 256 + t;
    int v = (i < N_NODES) ? indeg[i] : 0;
    s[t] = v;
    __syncthreads();
    for (int off = 1; off < 256; off <<= 1) {
        int x = (t >= off) ? s[t - off] : 0;
        __syncthreads();
        s[t] += x;
        __syncthreads();
    }
    if (i < N_NODES) {
        rp[i] = s[t] - v;                       // exclusive (block-local)
        dis[i] = rsqrtf((float)v + 1.0f);       // +1 = self loop
    }
    if (t == 255) bsum[blockIdx.x] = s[255];
}

// scan of block sums + gstart binary searches on idle threads
__global__ void k_scan2(int* __restrict__ bsum, const int* __restrict__ batch,
                        int* __restrict__ gstart) {
    __shared__ int s[512];
    int t = threadIdx.x;
    int v = (t < NB_SCAN) ? bsum[t] : 0;
    s[t] = v;
    __syncthreads();
    for (int off = 1; off < 512; off <<= 1) {
        int x = (t >= off) ? s[t - off] : 0;
        __syncthreads();
        s[t] += x;
        __syncthreads();
    }
    if (t < NB_SCAN) bsum[t] = s[t] - v;        // exclusive block offsets
    if (t <= N_GRAPHS) {                        // lower_bound(batch, t)
        int lo = 0, hi = N_NODES;
        while (lo < hi) {
            int mid = (lo + hi) >> 1;
            if (batch[mid] < t) lo = mid + 1; else hi = mid;
        }
        gstart[t] = lo;
    }
}

// ---------------------------------------------------------------- MFMA GEMM (fp16, 64-row tile, staged A+W, BK=64)
// Best-measured configuration (R12, 393.5us). Fused scatter streamed behind
// GEMM1 (+30us overlap, R9-vs-R10 bisect). The fused dispatch is latency-
// pinned at ~190us across 5 structural variants (BK, tile, occupancy,
// staged/direct, sync/async) — all counters <20% busy; left as-is.
#define BKV 64
#define LDSTR 72   // padded LDS row stride (16-bit elems); 144B rows -> 2-way alias (free)

template<int K, bool AFP32, bool FUSE_SCATTER>
__global__ __launch_bounds__(256) void k_gemm_mfma(const void* __restrict__ Av,
                                                   const _Float16* __restrict__ Wt,
                                                   _Float16* __restrict__ C,
                                                   int nrows,
                                                   const int* __restrict__ esrc,
                                                   const int* __restrict__ edst,
                                                   const int* __restrict__ rp,
                                                   const int* __restrict__ bsum,
                                                   const float* __restrict__ dis,
                                                   int* __restrict__ cursor,
                                                   uint2* __restrict__ csrw,
                                                   int gemm_blocks) {
    __shared__ ushort As[64 * LDSTR];    // 9.2 KB
    __shared__ ushort Bs[128 * LDSTR];   // 18.4 KB

    if (FUSE_SCATTER && (int)blockIdx.x >= gemm_blocks) {
        int e = (blockIdx.x - gemm_blocks) * 256 + threadIdx.x;
        if (e < N_EDGES) {
            int d = edst[e];
            int sv = esrc[e];
            int pos = atomicAdd(&cursor[d], 1);
            uint2 val;
            val.x = (uint)sv;
            val.y = __float_as_uint(dis[sv]);
            csrw[rp[d] + bsum[d >> 8] + pos] = val;
        }
        return;
    }

    const int t = threadIdx.x;
    const int row0 = blockIdx.x * 64;
    const int sa_row = t >> 2;           // A staging row 0..63
    const int sa_col = (t & 3) * 16;     // A staging k base (16 elems)
    const int sw_row = t >> 1;           // W staging row (n) 0..127
    const int sw_col = (t & 1) * 32;     // W staging k base (32 elems)
    const int l = t & 63;
    const int wv = t >> 6;
    const int wm = wv >> 1, wn = wv & 1; // wave 2x2: rows 32/wave, cols 64/wave
    const int lr = l & 15;
    const int lk8 = (l >> 4) * 8;
    const bool arow_ok = (row0 + sa_row < nrows);

    f32x4 acc[2][4];
    const f32x4 zero = {0.f, 0.f, 0.f, 0.f};
    #pragma unroll
    for (int m = 0; m < 2; ++m)
        #pragma unroll
        for (int n = 0; n < 4; ++n) acc[m][n] = zero;

    for (int k0 = 0; k0 < K; k0 += BKV) {
        // ---- stage A tile [64 rows][64 k] as fp16 (4 threads/row, 16 elems each) ----
        if (AFP32) {
            union { _Float16 h[16]; uint4 q[2]; } cv;
            float f[16];
            if (arow_ok) {
                const float4* Ap = (const float4*)((const float*)Av +
                    (size_t)(row0 + sa_row) * K + k0 + sa_col);
                #pragma unroll
                for (int i = 0; i < 4; ++i) *(float4*)&f[4 * i] = Ap[i];
            } else {
                #pragma unroll
                for (int i = 0; i < 16; ++i) f[i] = 0.f;
            }
            #pragma unroll
            for (int i = 0; i < 16; ++i) cv.h[i] = (_Float16)f[i];
            *(uint4*)&As[sa_row * LDSTR + sa_col]     = cv.q[0];
            *(uint4*)&As[sa_row * LDSTR + sa_col + 8] = cv.q[1];
        } else {
            uint4 q0 = {0, 0, 0, 0}, q1 = {0, 0, 0, 0};
            if (arow_ok) {
                const uint4* Ap = (const uint4*)((const _Float16*)Av +
                    (size_t)(row0 + sa_row) * K + k0 + sa_col);
                q0 = Ap[0]; q1 = Ap[1];
            }
            *(uint4*)&As[sa_row * LDSTR + sa_col]     = q0;
            *(uint4*)&As[sa_row * LDSTR + sa_col + 8] = q1;
        }
        // ---- stage W tile [128 n][64 k] (2 threads/row, 32 elems each) ----
        {
            const uint4* Wp = (const uint4*)(Wt + (size_t)sw_row * K + k0 + sw_col);
            uint4 w0 = Wp[0], w1 = Wp[1], w2 = Wp[2], w3 = Wp[3];
            *(uint4*)&Bs[sw_row * LDSTR + sw_col + 0]  = w0;
            *(uint4*)&Bs[sw_row * LDSTR + sw_col + 8]  = w1;
            *(uint4*)&Bs[sw_row * LDSTR + sw_col + 16] = w2;
            *(uint4*)&Bs[sw_row * LDSTR + sw_col + 24] = w3;
        }
        __syncthreads();

        #pragma unroll
        for (int ks2 = 0; ks2 < 2; ++ks2) {
            half8 a[2], b[4];
            #pragma unroll
            for (int m = 0; m < 2; ++m)
                a[m] = *(const half8*)&As[(wm * 32 + m * 16 + lr) * LDSTR + ks2 * 32 + lk8];
            #pragma unroll
            for (int n = 0; n < 4; ++n)
                b[n] = *(const half8*)&Bs[(wn * 64 + n * 16 + lr) * LDSTR + ks2 * 32 + lk8];
            #pragma unroll
            for (int m = 0; m < 2; ++m)
                #pragma unroll
                for (int n = 0; n < 4; ++n)
                    acc[m][n] = __builtin_amdgcn_mfma_f32_16x16x32_f16(a[m], b[n], acc[m][n], 0, 0, 0);
        }
        __syncthreads();
    }

    // ---- epilogue: C/D layout col=lane&15, row=(lane>>4)*4+j ----
    #pragma unroll
    for (int m = 0; m < 2; ++m) {
        #pragma unroll
        for (int n = 0; n < 4; ++n) {
            int col = wn * 64 + n * 16 + lr;
            #pragma unroll
            for (int j = 0; j < 4; ++j) {
                int row = row0 + wm * 32 + m * 16 + (l >> 4) * 4 + j;
                if (row < nrows)
                    C[(size_t)row * DIM_H + col] = (_Float16)acc[m][n][j];
            }
        }
    }
}

// ---------------------------------------------------------------- aggregation (R7 structure, fp16 features)
// 1 wave = 1 node; quarter-wave (16 lanes) x uint4 = one 256B row per quarter.
__device__ __forceinline__ void acc8(uint4 u, float w, float* a) {
    __half2 h0 = *(__half2*)&u.x;
    __half2 h1 = *(__half2*)&u.y;
    __half2 h2 = *(__half2*)&u.z;
    __half2 h3 = *(__half2*)&u.w;
    a[0] += __low2float(h0) * w; a[1] += __high2float(h0) * w;
    a[2] += __low2float(h1) * w; a[3] += __high2float(h1) * w;
    a[4] += __low2float(h2) * w; a[5] += __high2float(h2) * w;
    a[6] += __low2float(h3) * w; a[7] += __high2float(h3) * w;
}

__global__ __launch_bounds__(256) void k_agg(const _Float16* __restrict__ hin,
                                             const uint2* __restrict__ csrw,
                                             const int* __restrict__ rp,
                                             const int* __restrict__ bsum,
                                             const int* __restrict__ indeg,
                                             const float* __restrict__ dis,
                                             const float* __restrict__ bias,
                                             _Float16* __restrict__ hout) {
    int node = (blockIdx.x * 256 + threadIdx.x) >> 6;
    int lane = threadIdx.x & 63;
    if (node >= N_NODES) return;
    int q  = lane >> 4;          // quarter 0..3
    int cl = lane & 15;          // 8-channel group within row
    float di = dis[node];
    int beg = rp[node] + bsum[node >> 8];
    int cnt = indeg[node];

    float a[8] = {0.f, 0.f, 0.f, 0.f, 0.f, 0.f, 0.f, 0.f};

    // prologue group: {self, e0, e1, e2}
    {
        uint s; float w;
        if (q == 0)             { s = (uint)node; w = di * di; }
        else if (q - 1 < cnt)   { uint2 p = csrw[beg + q - 1]; s = p.x; w = __uint_as_float(p.y) * di; }
        else                    { s = (uint)node; w = 0.f; }
        uint4 u = ((const uint4*)(hin + (size_t)s * DIM_H))[cl];
        acc8(u, w, a);
    }
    const uint2* cp = csrw + beg + 3;
    int m = cnt - 3;
    int i = 0;
    for (; i + 8 <= m; i += 8) {
        uint2 p0 = cp[i + q];
        uint2 p1 = cp[i + 4 + q];
        float w0 = __uint_as_float(p0.y) * di;
        float w1 = __uint_as_float(p1.y) * di;
        uint4 u0 = ((const uint4*)(hin + (size_t)p0.x * DIM_H))[cl];
        uint4 u1 = ((const uint4*)(hin + (size_t)p1.x * DIM_H))[cl];
        acc8(u0, w0, a);
        acc8(u1, w1, a);
    }
    for (; i < m; i += 4) {
        int idx = i + q;
        uint s; float w;
        if (idx < m) { uint2 p = cp[idx]; s = p.x; w = __uint_as_float(p.y) * di; }
        else         { s = (uint)node;    w = 0.f; }
        uint4 u = ((const uint4*)(hin + (size_t)s * DIM_H))[cl];
        acc8(u, w, a);
    }

    #pragma unroll
    for (int j = 0; j < 8; ++j) {
        a[j] += __shfl_xor(a[j], 16);
        a[j] += __shfl_xor(a[j], 32);
    }

    if (q == 0) {
        float4 b0 = ((const float4*)bias)[cl * 2];
        float4 b1 = ((const float4*)bias)[cl * 2 + 1];
        __half2 h0 = __floats2half2_rn(fmaxf(a[0] + b0.x, 0.f), fmaxf(a[1] + b0.y, 0.f));
        __half2 h1 = __floats2half2_rn(fmaxf(a[2] + b0.z, 0.f), fmaxf(a[3] + b0.w, 0.f));
        __half2 h2 = __floats2half2_rn(fmaxf(a[4] + b1.x, 0.f), fmaxf(a[5] + b1.y, 0.f));
        __half2 h3 = __floats2half2_rn(fmaxf(a[6] + b1.z, 0.f), fmaxf(a[7] + b1.w, 0.f));
        uint4 o;
        o.x = *(uint*)&h0; o.y = *(uint*)&h1; o.z = *(uint*)&h2; o.w = *(uint*)&h3;
        ((uint4*)(hout + (size_t)node * DIM_H))[cl] = o;
    }
}

// ---------------------------------------------------------------- mean pool: per-split partials
#define PSPLIT 8
__global__ __launch_bounds__(256) void k_pool(const _Float16* __restrict__ h,
                                              const int* __restrict__ gstart,
                                              float* __restrict__ pooled2) {
    int g  = blockIdx.x >> 3;
    int sp = blockIdx.x & 7;
    int r0 = gstart[g], r1 = gstart[g + 1];
    int count = r1 - r0;
    int chunk = (count + PSPLIT - 1) / PSPLIT;
    int aS = r0 + sp * chunk;
    int bE = min(aS + chunk, r1);
    int c  = threadIdx.x & 63;       // uint channel pair
    int rr = threadIdx.x >> 6;       // row offset 0..3
    float s0a = 0.f, s1a = 0.f, s0b = 0.f, s1b = 0.f;
    int r = aS + rr;
    for (; r + 4 < bE; r += 8) {     // 2-way unroll, independent accumulators
        uint ua = ((const uint*)(h + (size_t)r * DIM_H))[c];
        uint ub = ((const uint*)(h + (size_t)(r + 4) * DIM_H))[c];
        __half2 ha = *(__half2*)&ua;
        __half2 hb = *(__half2*)&ub;
        s0a += __low2float(ha); s1a += __high2float(ha);
        s0b += __low2float(hb); s1b += __high2float(hb);
    }
    if (r < bE) {
        uint ua = ((const uint*)(h + (size_t)r * DIM_H))[c];
        __half2 ha = *(__half2*)&ua;
        s0a += __low2float(ha); s1a += __high2float(ha);
    }
    float s0 = s0a + s0b, s1 = s1a + s1b;
    __shared__ float sm0[4][64], sm1[4][64];
    sm0[rr][c] = s0; sm1[rr][c] = s1;
    __syncthreads();
    if (rr == 0) {
        float v0 = sm0[0][c] + sm0[1][c] + sm0[2][c] + sm0[3][c];
        float v1 = sm1[0][c] + sm1[1][c] + sm1[2][c] + sm1[3][c];
        float* dst = pooled2 + (size_t)(g * PSPLIT + sp) * DIM_H;
        dst[2 * c]     = v0;
        dst[2 * c + 1] = v1;
    }
}

// ---------------------------------------------------------------- head (sums 8 partials)
__global__ __launch_bounds__(128) void k_head(const float* __restrict__ pooled2,
                                              const int* __restrict__ gstart,
                                              const float* __restrict__ Wh,
                                              const float* __restrict__ bh,
                                              float* __restrict__ out) {
    int g = blockIdx.x;
    int c = threadIdx.x;
    float s = 0.f;
    #pragma unroll
    for (int sp = 0; sp < PSPLIT; ++sp)
        s += pooled2[(size_t)(g * PSPLIT + sp) * DIM_H + c];
    float cntg = (float)(gstart[g + 1] - gstart[g]);
    float e = s / fmaxf(cntg, 1.0f);
    __shared__ float s0[128], s1[128];
    s0[c] = e * Wh[c * 2 + 0];
    s1[c] = e * Wh[c * 2 + 1];
    __syncthreads();
    for (int off = 64; off > 0; off >>= 1) {
        if (c < off) { s0[c] += s0[c + off]; s1[c] += s1[c + off]; }
        __syncthreads();
    }
    if (c == 0) {
        out[g * 2 + 0] = s0[0] + bh[0];
        out[g * 2 + 1] = s1[0] + bh[1];
    }
}

// ---------------------------------------------------------------- launch
extern "C" void kernel_launch(void* const* d_in, const int* in_sizes, int n_in,
                              void* d_out, int out_size, void* d_ws, size_t ws_size,
                              hipStream_t stream) {
    const float* x    = (const float*)d_in[0];
    const int*   esrc = (const int*)d_in[1];
    const int*   edst = esrc + N_EDGES;
    const int*   batch= (const int*)d_in[2];
    const float* W1   = (const float*)d_in[3];
    const float* b1   = (const float*)d_in[4];
    const float* W2   = (const float*)d_in[5];
    const float* b2   = (const float*)d_in[6];
    const float* Wh   = (const float*)d_in[7];
    const float* bh   = (const float*)d_in[8];
    float* out = (float*)d_out;

    char* ws = (char*)d_ws;
    size_t off = 0;
    auto alloc = [&](size_t bytes) {
        void* p = ws + off;
        off += (bytes + 255) & ~(size_t)255;
        return p;
    };
    _Float16* bufZ   = (_Float16*)alloc((size_t)N_NODES * DIM_H * 2);
    _Float16* bufH   = (_Float16*)alloc((size_t)N_NODES * DIM_H * 2);
    float*    dis    = (float*)alloc((size_t)N_NODES * 4);
    int*      deg2   = (int*)  alloc((size_t)2 * N_NODES * 4);   // indeg | cursor
    int*      indeg  = deg2;
    int*      cursor = deg2 + N_NODES;
    int*      rp     = (int*)  alloc((size_t)N_NODES * 4);
    uint2*    csrw   = (uint2*)alloc((size_t)N_EDGES * 8);
    int*      bsum   = (int*)  alloc(512 * 4);
    float*    pooled2= (float*)alloc((size_t)N_GRAPHS * PSPLIT * DIM_H * 4);
    int*      gstart = (int*)  alloc((N_GRAPHS + 1) * 4);
    _Float16* W1t    = (_Float16*)alloc((size_t)DIM_IN * DIM_H * 2);
    _Float16* W2t    = (_Float16*)alloc((size_t)DIM_H * DIM_H * 2);

    hipMemsetAsync(deg2, 0, (size_t)2 * N_NODES * 4, stream);

    int convblocks = (DIM_IN * DIM_H + DIM_H * DIM_H + 255) / 256;
    k_convW  <<<convblocks, 256, 0, stream>>>(W1, W2, W1t, W2t);

    k_indeg  <<<(N_EDGES + 255) / 256, 256, 0, stream>>>(edst, indeg);
    k_scan1  <<<NB_SCAN, 256, 0, stream>>>(indeg, rp, bsum, dis);
    k_scan2  <<<1, 512, 0, stream>>>(bsum, batch, gstart);

    int gblocks = (N_NODES + 63) / 64;                   // 1563
    int scblocks = (N_EDGES + 255) / 256;                // 6250
    // GEMM1 with CSR scatter streamed behind it (proven +30us overlap, R9 vs R10)
    k_gemm_mfma<DIM_IN, true, true><<<gblocks + scblocks, 256, 0, stream>>>(
        x, W1t, bufZ, N_NODES, esrc, edst, rp, bsum, dis, cursor, csrw, gblocks);
    k_agg<<<(N_NODES + 3) / 4, 256, 0, stream>>>(bufZ, csrw, rp, bsum, indeg, dis, b1, bufH);
    k_gemm_mfma<DIM_H, false, false><<<gblocks, 256, 0, stream>>>(
        bufH, W2t, bufZ, N_NODES, nullptr, nullptr, nullptr, nullptr, nullptr, nullptr, nullptr, gblocks);
    k_agg<<<(N_NODES + 3) / 4, 256, 0, stream>>>(bufZ, csrw, rp, bsum, indeg, dis, b2, bufH);

    k_pool<<<N_GRAPHS * PSPLIT, 256, 0, stream>>>(bufH, gstart, pooled2);
    k_head<<<N_GRAPHS, 128, 0, stream>>>(pooled2, gstart, Wh, bh, out);
}

// Round 16
// 385.649 us; speedup vs baseline: 1.0591x; 1.0290x over previous
//
#include <hip/hip_runtime.h>
#include <hip/hip_bf16.h>
#include <hip/hip_fp16.h>

static constexpr int N_NODES  = 100000;
static constexpr int N_EDGES  = 1600000;
static constexpr int DIM_IN   = 768;
static constexpr int DIM_H    = 128;
static constexpr int N_GRAPHS = 64;
static constexpr int NB_SCAN  = (N_NODES + 255) / 256;   // 391

typedef __attribute__((ext_vector_type(8))) _Float16 half8;
typedef __attribute__((ext_vector_type(4))) float f32x4;

// ---------------------------------------------------------------- W convert (both layers, fp16 transposed)
__global__ void k_convW(const float* __restrict__ W1, const float* __restrict__ W2,
                        _Float16* __restrict__ W1t, _Float16* __restrict__ W2t) {
    int i = blockIdx.x * 256 + threadIdx.x;
    const int total1 = DIM_IN * DIM_H;
    if (i < total1) {
        int k = i >> 7, n = i & 127;
        W1t[(size_t)n * DIM_IN + k] = (_Float16)W1[i];
    } else if (i < total1 + DIM_H * DIM_H) {
        int j = i - total1;
        int k = j >> 7, n = j & 127;
        W2t[(size_t)n * DIM_H + k] = (_Float16)W2[j];
    }
}

// ---------------------------------------------------------------- scan (+dis fold)
__global__ void k_scan1(const int* __restrict__ indeg, int* __restrict__ rp,
                        int* __restrict__ bsum, float* __restrict__ dis) {
    __shared__ int s[256];
    int t = threadIdx.x;
    int i = blockIdx.x * 256 + t;
    int v = (i < N_NODES) ? indeg[i] : 0;
    s[t] = v;
    __syncthreads();
    for (int off = 1; off < 256; off <<= 1) {
        int x = (t >= off) ? s[t - off] : 0;
        __syncthreads();
        s[t] += x;
        __syncthreads();
    }
    if (i < N_NODES) {
        rp[i] = s[t] - v;                       // exclusive (block-local)
        dis[i] = rsqrtf((float)v + 1.0f);       // +1 = self loop
    }
    if (t == 255) bsum[blockIdx.x] = s[255];
}

// scan of block sums + gstart binary searches on idle threads
__global__ void k_scan2(int* __restrict__ bsum, const int* __restrict__ batch,
                        int* __restrict__ gstart) {
    __shared__ int s[512];
    int t = threadIdx.x;
    int v = (t < NB_SCAN) ? bsum[t] : 0;
    s[t] = v;
    __syncthreads();
    for (int off = 1; off < 512; off <<= 1) {
        int x = (t >= off) ? s[t - off] : 0;
        __syncthreads();
        s[t] += x;
        __syncthreads();
    }
    if (t < NB_SCAN) bsum[t] = s[t] - v;        // exclusive block offsets
    if (t <= N_GRAPHS) {                        // lower_bound(batch, t)
        int lo = 0, hi = N_NODES;
        while (lo < hi) {
            int mid = (lo + hi) >> 1;
            if (batch[mid] < t) lo = mid + 1; else hi = mid;
        }
        gstart[t] = lo;
    }
}

// ---------------------------------------------------------------- fixup: global row ptr + atomic cursor copy
__global__ void k_fixup(const int* __restrict__ rp, const int* __restrict__ bsum,
                        int* __restrict__ rpg, int* __restrict__ cursor2) {
    int i = blockIdx.x * 256 + threadIdx.x;
    if (i < N_NODES) {
        int v = rp[i] + bsum[i >> 8];
        rpg[i] = v;
        cursor2[i] = v;
    }
}

// ---------------------------------------------------------------- CSR scatter: single atomic returns global slot
// (3 random lines/edge: cursor2 atomic, dis[sv], csrw write — rp/bsum reads
// eliminated vs R12's 4-line form). No LDS -> full occupancy.
__global__ void k_scatter(const int* __restrict__ esrc, const int* __restrict__ edst,
                          const float* __restrict__ dis,
                          int* __restrict__ cursor2, uint2* __restrict__ csrw) {
    int e = blockIdx.x * 256 + threadIdx.x;
    if (e >= N_EDGES) return;
    int d = edst[e];
    int sv = esrc[e];
    int pos = atomicAdd(&cursor2[d], 1);
    uint2 val;
    val.x = (uint)sv;
    val.y = __float_as_uint(dis[sv]);
    csrw[pos] = val;
}

// ---------------------------------------------------------------- MFMA GEMM (fp16, 64-row tile, staged A+W, BK=64)
// R12-identical GEMM. FUSE_INDEG: 6250 indeg blocks streamed behind GEMM1
// (both are heads of their dependency chains -> legal overlap; scatter now
// runs standalone so it finally gets its own counters).
#define BKV 64
#define LDSTR 72   // padded LDS row stride (16-bit elems); 144B rows -> 2-way alias (free)

template<int K, bool AFP32, bool FUSE_INDEG>
__global__ __launch_bounds__(256) void k_gemm_mfma(const void* __restrict__ Av,
                                                   const _Float16* __restrict__ Wt,
                                                   _Float16* __restrict__ C,
                                                   int nrows,
                                                   const int* __restrict__ edst,
                                                   int* __restrict__ indeg,
                                                   int gemm_blocks) {
    __shared__ ushort As[64 * LDSTR];    // 9.2 KB
    __shared__ ushort Bs[128 * LDSTR];   // 18.4 KB

    if (FUSE_INDEG && (int)blockIdx.x >= gemm_blocks) {
        int e = (blockIdx.x - gemm_blocks) * 256 + threadIdx.x;
        if (e < N_EDGES) atomicAdd(&indeg[edst[e]], 1);
        return;
    }

    const int t = threadIdx.x;
    const int row0 = blockIdx.x * 64;
    const int sa_row = t >> 2;           // A staging row 0..63
    const int sa_col = (t & 3) * 16;     // A staging k base (16 elems)
    const int sw_row = t >> 1;           // W staging row (n) 0..127
    const int sw_col = (t & 1) * 32;     // W staging k base (32 elems)
    const int l = t & 63;
    const int wv = t >> 6;
    const int wm = wv >> 1, wn = wv & 1; // wave 2x2: rows 32/wave, cols 64/wave
    const int lr = l & 15;
    const int lk8 = (l >> 4) * 8;
    const bool arow_ok = (row0 + sa_row < nrows);

    f32x4 acc[2][4];
    const f32x4 zero = {0.f, 0.f, 0.f, 0.f};
    #pragma unroll
    for (int m = 0; m < 2; ++m)
        #pragma unroll
        for (int n = 0; n < 4; ++n) acc[m][n] = zero;

    for (int k0 = 0; k0 < K; k0 += BKV) {
        // ---- stage A tile [64 rows][64 k] as fp16 (4 threads/row, 16 elems each) ----
        if (AFP32) {
            union { _Float16 h[16]; uint4 q[2]; } cv;
            float f[16];
            if (arow_ok) {
                const float4* Ap = (const float4*)((const float*)Av +
                    (size_t)(row0 + sa_row) * K + k0 + sa_col);
                #pragma unroll
                for (int i = 0; i < 4; ++i) *(float4*)&f[4 * i] = Ap[i];
            } else {
                #pragma unroll
                for (int i = 0; i < 16; ++i) f[i] = 0.f;
            }
            #pragma unroll
            for (int i = 0; i < 16; ++i) cv.h[i] = (_Float16)f[i];
            *(uint4*)&As[sa_row * LDSTR + sa_col]     = cv.q[0];
            *(uint4*)&As[sa_row * LDSTR + sa_col + 8] = cv.q[1];
        } else {
            uint4 q0 = {0, 0, 0, 0}, q1 = {0, 0, 0, 0};
            if (arow_ok) {
                const uint4* Ap = (const uint4*)((const _Float16*)Av +
                    (size_t)(row0 + sa_row) * K + k0 + sa_col);
                q0 = Ap[0]; q1 = Ap[1];
            }
            *(uint4*)&As[sa_row * LDSTR + sa_col]     = q0;
            *(uint4*)&As[sa_row * LDSTR + sa_col + 8] = q1;
        }
        // ---- stage W tile [128 n][64 k] (2 threads/row, 32 elems each) ----
        {
            const uint4* Wp = (const uint4*)(Wt + (size_t)sw_row * K + k0 + sw_col);
            uint4 w0 = Wp[0], w1 = Wp[1], w2 = Wp[2], w3 = Wp[3];
            *(uint4*)&Bs[sw_row * LDSTR + sw_col + 0]  = w0;
            *(uint4*)&Bs[sw_row * LDSTR + sw_col + 8]  = w1;
            *(uint4*)&Bs[sw_row * LDSTR + sw_col + 16] = w2;
            *(uint4*)&Bs[sw_row * LDSTR + sw_col + 24] = w3;
        }
        __syncthreads();

        #pragma unroll
        for (int ks2 = 0; ks2 < 2; ++ks2) {
            half8 a[2], b[4];
            #pragma unroll
            for (int m = 0; m < 2; ++m)
                a[m] = *(const half8*)&As[(wm * 32 + m * 16 + lr) * LDSTR + ks2 * 32 + lk8];
            #pragma unroll
            for (int n = 0; n < 4; ++n)
                b[n] = *(const half8*)&Bs[(wn * 64 + n * 16 + lr) * LDSTR + ks2 * 32 + lk8];
            #pragma unroll
            for (int m = 0; m < 2; ++m)
                #pragma unroll
                for (int n = 0; n < 4; ++n)
                    acc[m][n] = __builtin_amdgcn_mfma_f32_16x16x32_f16(a[m], b[n], acc[m][n], 0, 0, 0);
        }
        __syncthreads();
    }

    // ---- epilogue: C/D layout col=lane&15, row=(lane>>4)*4+j ----
    #pragma unroll
    for (int m = 0; m < 2; ++m) {
        #pragma unroll
        for (int n = 0; n < 4; ++n) {
            int col = wn * 64 + n * 16 + lr;
            #pragma unroll
            for (int j = 0; j < 4; ++j) {
                int row = row0 + wm * 32 + m * 16 + (l >> 4) * 4 + j;
                if (row < nrows)
                    C[(size_t)row * DIM_H + col] = (_Float16)acc[m][n][j];
            }
        }
    }
}

// ---------------------------------------------------------------- aggregation (R7 structure, fp16 features, rpg)
// 1 wave = 1 node; quarter-wave (16 lanes) x uint4 = one 256B row per quarter.
__device__ __forceinline__ void acc8(uint4 u, float w, float* a) {
    __half2 h0 = *(__half2*)&u.x;
    __half2 h1 = *(__half2*)&u.y;
    __half2 h2 = *(__half2*)&u.z;
    __half2 h3 = *(__half2*)&u.w;
    a[0] += __low2float(h0) * w; a[1] += __high2float(h0) * w;
    a[2] += __low2float(h1) * w; a[3] += __high2float(h1) * w;
    a[4] += __low2float(h2) * w; a[5] += __high2float(h2) * w;
    a[6] += __low2float(h3) * w; a[7] += __high2float(h3) * w;
}

__global__ __launch_bounds__(256) void k_agg(const _Float16* __restrict__ hin,
                                             const uint2* __restrict__ csrw,
                                             const int* __restrict__ rpg,
                                             const int* __restrict__ indeg,
                                             const float* __restrict__ dis,
                                             const float* __restrict__ bias,
                                             _Float16* __restrict__ hout) {
    int node = (blockIdx.x * 256 + threadIdx.x) >> 6;
    int lane = threadIdx.x & 63;
    if (node >= N_NODES) return;
    int q  = lane >> 4;          // quarter 0..3
    int cl = lane & 15;          // 8-channel group within row
    float di = dis[node];
    int beg = rpg[node];
    int cnt = indeg[node];

    float a[8] = {0.f, 0.f, 0.f, 0.f, 0.f, 0.f, 0.f, 0.f};

    // prologue group: {self, e0, e1, e2}
    {
        uint s; float w;
        if (q == 0)             { s = (uint)node; w = di * di; }
        else if (q - 1 < cnt)   { uint2 p = csrw[beg + q - 1]; s = p.x; w = __uint_as_float(p.y) * di; }
        else                    { s = (uint)node; w = 0.f; }
        uint4 u = ((const uint4*)(hin + (size_t)s * DIM_H))[cl];
        acc8(u, w, a);
    }
    const uint2* cp = csrw + beg + 3;
    int m = cnt - 3;
    int i = 0;
    for (; i + 8 <= m; i += 8) {
        uint2 p0 = cp[i + q];
        uint2 p1 = cp[i + 4 + q];
        float w0 = __uint_as_float(p0.y) * di;
        float w1 = __uint_as_float(p1.y) * di;
        uint4 u0 = ((const uint4*)(hin + (size_t)p0.x * DIM_H))[cl];
        uint4 u1 = ((const uint4*)(hin + (size_t)p1.x * DIM_H))[cl];
        acc8(u0, w0, a);
        acc8(u1, w1, a);
    }
    for (; i < m; i += 4) {
        int idx = i + q;
        uint s; float w;
        if (idx < m) { uint2 p = cp[idx]; s = p.x; w = __uint_as_float(p.y) * di; }
        else         { s = (uint)node;    w = 0.f; }
        uint4 u = ((const uint4*)(hin + (size_t)s * DIM_H))[cl];
        acc8(u, w, a);
    }

    #pragma unroll
    for (int j = 0; j < 8; ++j) {
        a[j] += __shfl_xor(a[j], 16);
        a[j] += __shfl_xor(a[j], 32);
    }

    if (q == 0) {
        float4 b0 = ((const float4*)bias)[cl * 2];
        float4 b1 = ((const float4*)bias)[cl * 2 + 1];
        __half2 h0 = __floats2half2_rn(fmaxf(a[0] + b0.x, 0.f), fmaxf(a[1] + b0.y, 0.f));
        __half2 h1 = __floats2half2_rn(fmaxf(a[2] + b0.z, 0.f), fmaxf(a[3] + b0.w, 0.f));
        __half2 h2 = __floats2half2_rn(fmaxf(a[4] + b1.x, 0.f), fmaxf(a[5] + b1.y, 0.f));
        __half2 h3 = __floats2half2_rn(fmaxf(a[6] + b1.z, 0.f), fmaxf(a[7] + b1.w, 0.f));
        uint4 o;
        o.x = *(uint*)&h0; o.y = *(uint*)&h1; o.z = *(uint*)&h2; o.w = *(uint*)&h3;
        ((uint4*)(hout + (size_t)node * DIM_H))[cl] = o;
    }
}

// ---------------------------------------------------------------- mean pool: per-split partials
#define PSPLIT 8
__global__ __launch_bounds__(256) void k_pool(const _Float16* __restrict__ h,
                                              const int* __restrict__ gstart,
                                              float* __restrict__ pooled2) {
    int g  = blockIdx.x >> 3;
    int sp = blockIdx.x & 7;
    int r0 = gstart[g], r1 = gstart[g + 1];
    int count = r1 - r0;
    int chunk = (count + PSPLIT - 1) / PSPLIT;
    int aS = r0 + sp * chunk;
    int bE = min(aS + chunk, r1);
    int c  = threadIdx.x & 63;       // uint channel pair
    int rr = threadIdx.x >> 6;       // row offset 0..3
    float s0a = 0.f, s1a = 0.f, s0b = 0.f, s1b = 0.f;
    int r = aS + rr;
    for (; r + 4 < bE; r += 8) {     // 2-way unroll, independent accumulators
        uint ua = ((const uint*)(h + (size_t)r * DIM_H))[c];
        uint ub = ((const uint*)(h + (size_t)(r + 4) * DIM_H))[c];
        __half2 ha = *(__half2*)&ua;
        __half2 hb = *(__half2*)&ub;
        s0a += __low2float(ha); s1a += __high2float(ha);
        s0b += __low2float(hb); s1b += __high2float(hb);
    }
    if (r < bE) {
        uint ua = ((const uint*)(h + (size_t)r * DIM_H))[c];
        __half2 ha = *(__half2*)&ua;
        s0a += __low2float(ha); s1a += __high2float(ha);
    }
    float s0 = s0a + s0b, s1 = s1a + s1b;
    __shared__ float sm0[4][64], sm1[4][64];
    sm0[rr][c] = s0; sm1[rr][c] = s1;
    __syncthreads();
    if (rr == 0) {
        float v0 = sm0[0][c] + sm0[1][c] + sm0[2][c] + sm0[3][c];
        float v1 = sm1[0][c] + sm1[1][c] + sm1[2][c] + sm1[3][c];
        float* dst = pooled2 + (size_t)(g * PSPLIT + sp) * DIM_H;
        dst[2 * c]     = v0;
        dst[2 * c + 1] = v1;
    }
}

// ---------------------------------------------------------------- head (sums 8 partials)
__global__ __launch_bounds__(128) void k_head(const float* __restrict__ pooled2,
                                              const int* __restrict__ gstart,
                                              const float* __restrict__ Wh,
                                              const float* __restrict__ bh,
                                              float* __restrict__ out) {
    int g = blockIdx.x;
    int c = threadIdx.x;
    float s = 0.f;
    #pragma unroll
    for (int sp = 0; sp < PSPLIT; ++sp)
        s += pooled2[(size_t)(g * PSPLIT + sp) * DIM_H + c];
    float cntg = (float)(gstart[g + 1] - gstart[g]);
    float e = s / fmaxf(cntg, 1.0f);
    __shared__ float s0[128], s1[128];
    s0[c] = e * Wh[c * 2 + 0];
    s1[c] = e * Wh[c * 2 + 1];
    __syncthreads();
    for (int off = 64; off > 0; off >>= 1) {
        if (c < off) { s0[c] += s0[c + off]; s1[c] += s1[c + off]; }
        __syncthreads();
    }
    if (c == 0) {
        out[g * 2 + 0] = s0[0] + bh[0];
        out[g * 2 + 1] = s1[0] + bh[1];
    }
}

// ---------------------------------------------------------------- launch
extern "C" void kernel_launch(void* const* d_in, const int* in_sizes, int n_in,
                              void* d_out, int out_size, void* d_ws, size_t ws_size,
                              hipStream_t stream) {
    const float* x    = (const float*)d_in[0];
    const int*   esrc = (const int*)d_in[1];
    const int*   edst = esrc + N_EDGES;
    const int*   batch= (const int*)d_in[2];
    const float* W1   = (const float*)d_in[3];
    const float* b1   = (const float*)d_in[4];
    const float* W2   = (const float*)d_in[5];
    const float* b2   = (const float*)d_in[6];
    const float* Wh   = (const float*)d_in[7];
    const float* bh   = (const float*)d_in[8];
    float* out = (float*)d_out;

    char* ws = (char*)d_ws;
    size_t off = 0;
    auto alloc = [&](size_t bytes) {
        void* p = ws + off;
        off += (bytes + 255) & ~(size_t)255;
        return p;
    };
    _Float16* bufZ   = (_Float16*)alloc((size_t)N_NODES * DIM_H * 2);
    _Float16* bufH   = (_Float16*)alloc((size_t)N_NODES * DIM_H * 2);
    float*    dis    = (float*)alloc((size_t)N_NODES * 4);
    int*      indeg  = (int*)  alloc((size_t)N_NODES * 4);
    int*      rp     = (int*)  alloc((size_t)N_NODES * 4);
    int*      rpg    = (int*)  alloc((size_t)N_NODES * 4);
    int*      cursor2= (int*)  alloc((size_t)N_NODES * 4);
    uint2*    csrw   = (uint2*)alloc((size_t)N_EDGES * 8);
    int*      bsum   = (int*)  alloc(512 * 4);
    float*    pooled2= (float*)alloc((size_t)N_GRAPHS * PSPLIT * DIM_H * 4);
    int*      gstart = (int*)  alloc((N_GRAPHS + 1) * 4);
    _Float16* W1t    = (_Float16*)alloc((size_t)DIM_IN * DIM_H * 2);
    _Float16* W2t    = (_Float16*)alloc((size_t)DIM_H * DIM_H * 2);

    hipMemsetAsync(indeg, 0, (size_t)N_NODES * 4, stream);

    int convblocks = (DIM_IN * DIM_H + DIM_H * DIM_H + 255) / 256;
    k_convW  <<<convblocks, 256, 0, stream>>>(W1, W2, W1t, W2t);

    int gblocks = (N_NODES + 63) / 64;                   // 1563
    int eblocks = (N_EDGES + 255) / 256;                 // 6250
    // GEMM1 with indeg streamed behind it (both heads of their dep chains)
    k_gemm_mfma<DIM_IN, true, true><<<gblocks + eblocks, 256, 0, stream>>>(
        x, W1t, bufZ, N_NODES, edst, indeg, gblocks);
    k_scan1  <<<NB_SCAN, 256, 0, stream>>>(indeg, rp, bsum, dis);
    k_scan2  <<<1, 512, 0, stream>>>(bsum, batch, gstart);
    k_fixup  <<<NB_SCAN, 256, 0, stream>>>(rp, bsum, rpg, cursor2);
    k_scatter<<<eblocks, 256, 0, stream>>>(esrc, edst, dis, cursor2, csrw);

    k_agg<<<(N_NODES + 3) / 4, 256, 0, stream>>>(bufZ, csrw, rpg, indeg, dis, b1, bufH);
    k_gemm_mfma<DIM_H, false, false><<<gblocks, 256, 0, stream>>>(
        bufH, W2t, bufZ, N_NODES, nullptr, nullptr, gblocks);
    k_agg<<<(N_NODES + 3) / 4, 256, 0, stream>>>(bufZ, csrw, rpg, indeg, dis, b2, bufH);

    k_pool<<<N_GRAPHS * PSPLIT, 256, 0, stream>>>(bufH, gstart, pooled2);
    k_head<<<N_GRAPHS, 128, 0, stream>>>(pooled2, gstart, Wh, bh, out);
}